// Round 9
// baseline (407.655 us; speedup 1.0000x reference)
//
#include <hip/hip_runtime.h>
#include <stdint.h>

#define N_NODES 100000
#define N_EDGES 1600000
#define D 128
#define NBUCK 196          // ceil(N_NODES/512); bucket b = dst >> 9
#define BSTRIDE 9216       // fixed pairs region per bucket (mean 8163, +11 sigma)
#define PCHUNK 2048        // edges per k_part block (16KB x2 LDS -> 4 blocks/CU)
#define QTILE 32           // nodes per fused block
#define NTILE (N_NODES / QTILE)   // 3125 exact
#define CASTB 3125         // 512-thread cast blocks: 3125*512*8 = 12.8M floats exact
#define WPACKB 128         // 128*512 = 65536 weight elements (both layers)

typedef unsigned int uint32;
typedef __attribute__((ext_vector_type(8))) short short8;   // 8 bf16 = 4 VGPRs
typedef __attribute__((ext_vector_type(4))) float f32x4;

__device__ __forceinline__ unsigned short f2bf(float f) {
  unsigned u = __builtin_bit_cast(unsigned, f);
  u += 0x7fffu + ((u >> 16) & 1u);          // round-to-nearest-even
  return (unsigned short)(u >> 16);
}
__device__ __forceinline__ float bflo(unsigned v) {
  return __builtin_bit_cast(float, v << 16);
}
__device__ __forceinline__ float bfhi(unsigned v) {
  return __builtin_bit_cast(float, v & 0xffff0000u);
}

// ---------------- CSR build (2 passes over edges) ------
// r3 lesson: no per-edge global atomic scatter (15x write amplification).
// r0/r7 lesson: no segmented-accumulate branches inside gather loops.

__global__ __launch_bounds__(256) void k_part(const int* __restrict__ src,
                                              const int* __restrict__ dst,
                                              int* __restrict__ bcnt,
                                              uint2* __restrict__ pairs) {
  __shared__ uint2 buff[PCHUNK];     // 16 KB
  __shared__ uint2 sorted[PCHUNK];   // 16 KB
  __shared__ int hist[256], stmp[256], loff[256], cpos[256], base[256];
  int tid = threadIdx.x;
  int e0 = blockIdx.x * PCHUNK;
  int nv = N_EDGES - e0;
  if (nv > PCHUNK) nv = PCHUNK;

  hist[tid] = 0;
  __syncthreads();
  for (int i = tid; i < nv; i += 256) {
    int d = dst[e0 + i];
    int s = src[e0 + i];
    buff[i] = make_uint2((uint32)d, (uint32)s);
    atomicAdd(&hist[d >> 9], 1);
  }
  __syncthreads();
  int v = hist[tid];
  stmp[tid] = v;
  __syncthreads();
  for (int off = 1; off < 256; off <<= 1) {
    int t = (tid >= off) ? stmp[tid - off] : 0;
    __syncthreads();
    stmp[tid] += t;
    __syncthreads();
  }
  loff[tid] = stmp[tid] - v;
  cpos[tid] = stmp[tid] - v;
  base[tid] = (v > 0) ? atomicAdd(&bcnt[tid], v) : 0;   // reserve run in bucket region
  __syncthreads();
  for (int i = tid; i < nv; i += 256) {
    uint2 p = buff[i];
    int r = atomicAdd(&cpos[p.x >> 9], 1);
    sorted[r] = p;
  }
  __syncthreads();
  for (int i = tid; i < nv; i += 256) {
    uint2 p = sorted[i];
    int b = (int)(p.x >> 9);
    int local = base[b] + (i - loff[b]);
    if (local < BSTRIDE)                                // det. input: never trips
      pairs[(size_t)b * BSTRIDE + local] = p;
  }
}

// Merged dispatch: blocks [0,NBUCK) build per-bucket rowptr+csr; remaining
// blocks do x-cast + W-pack on the CUs the 196 csr blocks leave idle.
__global__ __launch_bounds__(512) void k_csr_prep(
    const uint2* __restrict__ pairs, const int* __restrict__ bcnt,
    int* __restrict__ rowptr, int* __restrict__ csr,
    const float* __restrict__ x, unsigned short* __restrict__ xb,
    const float* __restrict__ Wl1, const float* __restrict__ Wr1,
    const float* __restrict__ Wl2, const float* __restrict__ Wr2,
    unsigned short* __restrict__ Wp1, unsigned short* __restrict__ Wp2) {
  __shared__ int hist[512], off[512], cur[512], scn[512];
  int tid = threadIdx.x;
  int blk = blockIdx.x;

  if (blk >= NBUCK) {
    int pb = blk - NBUCK;
    if (pb < CASTB) {                     // x f32 -> bf16, 8 elems/thread
      size_t i = (size_t)pb * 512 + tid;  // < 1.6M exact
      float4 a = *reinterpret_cast<const float4*>(x + i * 8);
      float4 c = *reinterpret_cast<const float4*>(x + i * 8 + 4);
      uint4 o;
      o.x = (uint32)f2bf(a.x) | ((uint32)f2bf(a.y) << 16);
      o.y = (uint32)f2bf(a.z) | ((uint32)f2bf(a.w) << 16);
      o.z = (uint32)f2bf(c.x) | ((uint32)f2bf(c.y) << 16);
      o.w = (uint32)f2bf(c.z) | ((uint32)f2bf(c.w) << 16);
      *reinterpret_cast<uint4*>(xb + i * 8) = o;
    } else {                              // pack both layers' W into B-frag order
      int t = (pb - CASTB) * 512 + tid;   // < 65536 exact
      int which = t >> 15;
      int tt = t & 32767;
      int j = tt & 7;
      int lane = (tt >> 3) & 63;
      int tile = (tt >> 9) & 1;
      int ks = (tt >> 10) & 7;
      int ng = (tt >> 13) & 3;
      int k = ks * 32 + (lane >> 4) * 8 + j;
      int n = ng * 32 + tile * 16 + (lane & 15);
      const float* Wl = which ? Wl2 : Wl1;
      const float* Wr = which ? Wr2 : Wr1;
      float w = (k < 128) ? Wl[k * 128 + n] : Wr[(k - 128) * 128 + n];
      (which ? Wp2 : Wp1)[tt] = f2bf(w);
    }
    return;
  }

  int b = blk;
  // inclusive scan of bucket counts -> bucket base for this block
  int bv = (tid < NBUCK) ? bcnt[tid] : 0;
  scn[tid] = bv;
  __syncthreads();
  for (int o = 1; o < 512; o <<= 1) {
    int t = (tid >= o) ? scn[tid - o] : 0;
    __syncthreads();
    scn[tid] += t;
    __syncthreads();
  }
  int bb = (b == 0) ? 0 : scn[b - 1];
  if (b == NBUCK - 1 && tid == 0) rowptr[N_NODES] = scn[NBUCK - 1];

  int lo = b << 9;
  int hi = lo + 512;
  if (hi > N_NODES) hi = N_NODES;
  int ne = bcnt[b];
  if (ne > BSTRIDE) ne = BSTRIDE;
  const uint2* pb2 = pairs + (size_t)b * BSTRIDE;

  hist[tid] = 0;
  __syncthreads();
  for (int i = tid; i < ne; i += 512) atomicAdd(&hist[(int)pb2[i].x - lo], 1);
  __syncthreads();
  int v = hist[tid];
  off[tid] = v;
  __syncthreads();
  for (int o = 1; o < 512; o <<= 1) {
    int t = (tid >= o) ? off[tid - o] : 0;
    __syncthreads();
    off[tid] += t;
    __syncthreads();
  }
  off[tid] -= v;               // exclusive
  cur[tid] = off[tid];
  if (lo + tid < hi) rowptr[lo + tid] = bb + off[tid];
  __syncthreads();
  for (int i = tid; i < ne; i += 512) {
    int d = (int)pb2[i].x - lo;
    int slot = atomicAdd(&cur[d], 1);
    csr[bb + slot] = (int)pb2[i].y;
  }
}

// ---------------- fused: work-stealing gather + MFMA GEMM ----------------
// Phase 1: 8 x 16-lane groups pop WHOLE nodes from an LDS queue; inner gather
// loop is byte-identical to the proven 57.2us k_mean (branch-free, 8-deep).
// Tail ratio ~1.09 vs r6's fixed-assignment 1.55 (measured 88.5/57.2).
// Phase 2 = r6's verified MFMA mapping, K-halved register staging.

#define ACC8(v)                                          \
  acc[0] += bflo(v.x); acc[1] += bfhi(v.x);              \
  acc[2] += bflo(v.y); acc[3] += bfhi(v.y);              \
  acc[4] += bflo(v.z); acc[5] += bfhi(v.z);              \
  acc[6] += bflo(v.w); acc[7] += bfhi(v.w);

__global__ __launch_bounds__(128, 6) void k_fused(
    const unsigned short* __restrict__ table,   // gather table AND x-half rows
    const int* __restrict__ rowptr, const int* __restrict__ csr,
    const unsigned short* __restrict__ Wp, const float* __restrict__ bias,
    void* __restrict__ outp, int relu_bf16_out) {
  __shared__ unsigned short meanB[QTILE * 128];   // 8 KB, XOR-swizzled 16B groups
  __shared__ int qS;
  int tid = threadIdx.x;
  int lane = tid & 63;
  int l = tid & 15;          // 16B lane within row
  int n0 = blockIdx.x * QTILE;

  if (tid == 0) qS = 0;
  __syncthreads();

  // ---- phase 1: work-stealing per-node gather ----
  for (;;) {
    int n;
    if (l == 0) n = atomicAdd(&qS, 1);
    n = __shfl(n, lane & 48);        // broadcast from group leader
    if (n >= QTILE) break;
    int node = n0 + n;
    int beg = rowptr[node], end = rowptr[node + 1];
    float acc[8] = {0.f, 0.f, 0.f, 0.f, 0.f, 0.f, 0.f, 0.f};
    int e = beg;
    for (; e + 8 <= end; e += 8) {   // 8 gathers in flight (r4 exact)
      int s0 = csr[e], s1 = csr[e + 1], s2 = csr[e + 2], s3 = csr[e + 3];
      int s4 = csr[e + 4], s5 = csr[e + 5], s6 = csr[e + 6], s7 = csr[e + 7];
      uint4 v0 = *reinterpret_cast<const uint4*>(table + (size_t)s0 * D + l * 8);
      uint4 v1 = *reinterpret_cast<const uint4*>(table + (size_t)s1 * D + l * 8);
      uint4 v2 = *reinterpret_cast<const uint4*>(table + (size_t)s2 * D + l * 8);
      uint4 v3 = *reinterpret_cast<const uint4*>(table + (size_t)s3 * D + l * 8);
      uint4 v4 = *reinterpret_cast<const uint4*>(table + (size_t)s4 * D + l * 8);
      uint4 v5 = *reinterpret_cast<const uint4*>(table + (size_t)s5 * D + l * 8);
      uint4 v6 = *reinterpret_cast<const uint4*>(table + (size_t)s6 * D + l * 8);
      uint4 v7 = *reinterpret_cast<const uint4*>(table + (size_t)s7 * D + l * 8);
      ACC8(v0) ACC8(v1) ACC8(v2) ACC8(v3)
      ACC8(v4) ACC8(v5) ACC8(v6) ACC8(v7)
    }
    for (; e + 4 <= end; e += 4) {
      int s0 = csr[e], s1 = csr[e + 1], s2 = csr[e + 2], s3 = csr[e + 3];
      uint4 v0 = *reinterpret_cast<const uint4*>(table + (size_t)s0 * D + l * 8);
      uint4 v1 = *reinterpret_cast<const uint4*>(table + (size_t)s1 * D + l * 8);
      uint4 v2 = *reinterpret_cast<const uint4*>(table + (size_t)s2 * D + l * 8);
      uint4 v3 = *reinterpret_cast<const uint4*>(table + (size_t)s3 * D + l * 8);
      ACC8(v0) ACC8(v1) ACC8(v2) ACC8(v3)
    }
    for (; e < end; ++e) {
      int s0 = csr[e];
      uint4 v0 = *reinterpret_cast<const uint4*>(table + (size_t)s0 * D + l * 8);
      ACC8(v0)
    }
    float inv = (end > beg) ? 1.0f / (float)(end - beg) : 0.0f;
    uint4 o;
    o.x = (uint32)f2bf(acc[0] * inv) | ((uint32)f2bf(acc[1] * inv) << 16);
    o.y = (uint32)f2bf(acc[2] * inv) | ((uint32)f2bf(acc[3] * inv) << 16);
    o.z = (uint32)f2bf(acc[4] * inv) | ((uint32)f2bf(acc[5] * inv) << 16);
    o.w = (uint32)f2bf(acc[6] * inv) | ((uint32)f2bf(acc[7] * inv) << 16);
    // swizzled: content-group l -> slot l^(n&15)  (matches phase-2 read)
    *reinterpret_cast<uint4*>(&meanB[n * 128 + (l ^ (n & 15)) * 8]) = o;
  }
  __syncthreads();

  // ---- phase 2: [mean | x] @ Wp (r6's verified mapping; K-halved regs) ----
  int w = tid >> 6;          // wave 0..1
  int q = lane >> 4;
  int r = lane & 15;

  for (int c = 0; c < 2; ++c) {
    int cq = w * 2 + c;      // col-quarter 0..3
    float bia0 = bias[cq * 32 + r];
    float bia1 = bias[cq * 32 + 16 + r];
    const unsigned short* wp = Wp + (size_t)cq * 8192 + lane * 8;
    for (int rt = 0; rt < 2; ++rt) {
      int arow = rt * 16 + r;
      f32x4 c0 = {0.f, 0.f, 0.f, 0.f}, c1 = {0.f, 0.f, 0.f, 0.f};
      {  // K-half 0: mean (LDS)
        short8 A[4], B0[4], B1[4];
#pragma unroll
        for (int ks = 0; ks < 4; ++ks) {
          int slot = (ks * 4 + q) ^ r;
          A[ks] = *reinterpret_cast<const short8*>(&meanB[arow * 128 + slot * 8]);
          B0[ks] = *reinterpret_cast<const short8*>(wp + (ks * 2 + 0) * 512);
          B1[ks] = *reinterpret_cast<const short8*>(wp + (ks * 2 + 1) * 512);
        }
#pragma unroll
        for (int ks = 0; ks < 4; ++ks) {
          c0 = __builtin_amdgcn_mfma_f32_16x16x32_bf16(A[ks], B0[ks], c0, 0, 0, 0);
          c1 = __builtin_amdgcn_mfma_f32_16x16x32_bf16(A[ks], B1[ks], c1, 0, 0, 0);
        }
      }
      {  // K-half 1: x (global)
        const unsigned short* ax = table + (size_t)(n0 + arow) * D + q * 8;
        short8 A[4], B0[4], B1[4];
#pragma unroll
        for (int ks = 0; ks < 4; ++ks) {
          A[ks] = *reinterpret_cast<const short8*>(ax + ks * 32);
          B0[ks] = *reinterpret_cast<const short8*>(wp + ((ks + 4) * 2 + 0) * 512);
          B1[ks] = *reinterpret_cast<const short8*>(wp + ((ks + 4) * 2 + 1) * 512);
        }
#pragma unroll
        for (int ks = 0; ks < 4; ++ks) {
          c0 = __builtin_amdgcn_mfma_f32_16x16x32_bf16(A[ks], B0[ks], c0, 0, 0, 0);
          c1 = __builtin_amdgcn_mfma_f32_16x16x32_bf16(A[ks], B1[ks], c1, 0, 0, 0);
        }
      }
      int orow = n0 + rt * 16 + q * 4;   // C: col=lane&15, row=quad*4+reg
      if (relu_bf16_out) {
        unsigned short* ob = (unsigned short*)outp + (size_t)orow * D + cq * 32 + r;
#pragma unroll
        for (int gg = 0; gg < 4; ++gg) {
          ob[(size_t)gg * D] = f2bf(fmaxf(c0[gg] + bia0, 0.f));
          ob[(size_t)gg * D + 16] = f2bf(fmaxf(c1[gg] + bia1, 0.f));
        }
      } else {
        float* of = (float*)outp + (size_t)orow * D + cq * 32 + r;
#pragma unroll
        for (int gg = 0; gg < 4; ++gg) {
          of[(size_t)gg * D] = c0[gg] + bia0;
          of[(size_t)gg * D + 16] = c1[gg] + bia1;
        }
      }
    }
  }
}

// ---------------- launch ----------------

extern "C" void kernel_launch(void* const* d_in, const int* in_sizes, int n_in,
                              void* d_out, int out_size, void* d_ws, size_t ws_size,
                              hipStream_t stream) {
  const float* x   = (const float*)d_in[0];
  const int*   ei  = (const int*)d_in[1];
  const float* Wl1 = (const float*)d_in[2];
  const float* Wr1 = (const float*)d_in[3];
  const float* b1  = (const float*)d_in[4];
  const float* Wl2 = (const float*)d_in[5];
  const float* Wr2 = (const float*)d_in[6];
  const float* b2  = (const float*)d_in[7];
  float* out = (float*)d_out;

  const int* esrc = ei;
  const int* edst = ei + N_EDGES;

  char* p = (char*)d_ws;
  auto take = [&](size_t bytes) {
    char* q = p;
    p += (bytes + 255) & ~(size_t)255;
    return q;
  };
  int* bcnt   = (int*)take(256 * 4);
  int* rowptr = (int*)take((size_t)(N_NODES + 1) * 4);
  int* csr    = (int*)take((size_t)N_EDGES * 4);
  uint2* pairs = (uint2*)take((size_t)NBUCK * BSTRIDE * 8);   // 14.5 MB
  unsigned short* xb  = (unsigned short*)take((size_t)N_NODES * D * 2);
  unsigned short* hb  = (unsigned short*)take((size_t)N_NODES * D * 2);
  unsigned short* Wp1 = (unsigned short*)take(256 * 128 * 2);
  unsigned short* Wp2 = (unsigned short*)take(256 * 128 * 2);

  const int npart = (N_EDGES + PCHUNK - 1) / PCHUNK;   // 782

  // CSR build: partition -> (per-bucket rowptr+csr || prep on idle CUs)
  hipMemsetAsync(bcnt, 0, 256 * 4, stream);
  k_part<<<npart, 256, 0, stream>>>(esrc, edst, bcnt, pairs);
  k_csr_prep<<<NBUCK + CASTB + WPACKB, 512, 0, stream>>>(
      pairs, bcnt, rowptr, csr, x, xb, Wl1, Wr1, Wl2, Wr2, Wp1, Wp2);

  // layer 1: hb = relu([mean(xb)|xb] @ Wp1 + b1)   (bf16 out)
  k_fused<<<NTILE, 128, 0, stream>>>(xb, rowptr, csr, Wp1, b1, hb, 1);
  // layer 2: out = [mean(hb)|hb] @ Wp2 + b2        (f32 out)
  k_fused<<<NTILE, 128, 0, stream>>>(hb, rowptr, csr, Wp2, b2, out, 0);
}